// Round 5
// baseline (17123.273 us; speedup 1.0000x reference)
//
#include <hip/hip_runtime.h>
#include <stdint.h>
#include <math.h>

constexpr int NN = 2048;   // nodes
constexpr int NA = 2048;   // ants
constexpr int NS = 2047;   // steps (N-1)
constexpr int NROWS = NS * NA;          // 4,192,256 (row id r = s*2048 + a)
constexpr int NWAVES = 2048 * 4;        // persistent: one generation, 8/SIMD

struct OvfRec { uint32_t cnt; uint32_t n[16]; float g[16]; };

constexpr int    OVF_CAP   = 32768;
constexpr size_t OFF_KEYS  = 1024;
constexpr size_t OFF_SLOTS = 32768;
constexpr size_t OFF_OVF   = OFF_SLOTS + (size_t)NS * NA * 4;
constexpr size_t OFF_PATHS = OFF_OVF + (size_t)OVF_CAP * sizeof(OvfRec);
constexpr size_t OFF_PLEN  = OFF_PATHS + (size_t)NA * NN * 2;
// total ws ~29.5 MB

// ---- Threefry-2x32, 20 rounds (jax partitionable counter mode) ----
__device__ __forceinline__ uint2 tf2x32(uint32_t k0, uint32_t k1,
                                        uint32_t x0, uint32_t x1) {
  const uint32_t k2 = k0 ^ k1 ^ 0x1BD11BDAu;
  x0 += k0; x1 += k1;
#define TFR(r) { x0 += x1; x1 = __builtin_rotateleft32(x1, r) ^ x0; }
  TFR(13) TFR(15) TFR(26) TFR(6)
  x0 += k1; x1 += k2 + 1u;
  TFR(17) TFR(29) TFR(16) TFR(24)
  x0 += k2; x1 += k0 + 2u;
  TFR(13) TFR(15) TFR(26) TFR(6)
  x0 += k0; x1 += k1 + 3u;
  TFR(17) TFR(29) TFR(16) TFR(24)
  x0 += k1; x1 += k2 + 4u;
  TFR(13) TFR(15) TFR(26) TFR(6)
  x0 += k2; x1 += k0 + 5u;
#undef TFR
  return make_uint2(x0, x1);
}

// g = -log(-log(u)), fp32 intermediate rounding via double log (matches XLA
// f32 log to ~1 ulp); u from 23-bit mantissa m, u==0 -> tiny.
__device__ __forceinline__ float gumbel_from_m(uint32_t m) {
  float u = __uint_as_float(0x3f800000u | m) - 1.0f;
  if (m == 0u) u = 1.17549435e-38f;
  float t1 = (float)log((double)u);
  float t2 = (float)log(-(double)t1);
  return -t2;
}

// ---- per-step keys: jax.random.split(key(42), 2047), partitionable ----
__global__ void k_keys(uint32_t* __restrict__ keys) {
  int i = blockIdx.x * 256 + threadIdx.x;
  if (i >= NS) return;
  uint2 o = tf2x32(0u, 42u, 0u, (uint32_t)i);
  keys[2 * i] = o.x; keys[2 * i + 1] = o.y;
}

// ---- global max of weights = pher * heur^2 ----
__global__ void k_wmax(const float* __restrict__ pher, const float* __restrict__ heur,
                       uint32_t* __restrict__ wmax_bits) {
  int tid = blockIdx.x * blockDim.x + threadIdx.x;
  int stride = gridDim.x * blockDim.x;
  float m = 0.f;
  for (int i = tid; i < NN * NN; i += stride) {
    float h = heur[i];
    m = fmaxf(m, pher[i] * (h * h));
  }
  for (int off = 32; off; off >>= 1) m = fmaxf(m, __shfl_xor(m, off));
  if ((threadIdx.x & 63) == 0) atomicMax((unsigned int*)wmax_bits, __float_as_uint(m));
}

// ---- Phase 1: persistent waves. 8192 waves (one resident generation),
// each loops ~512 rows. Scalar row->(s,a), per-wave wmax, software-pipelined
// scalar key prefetch. Per-lane top-2 via tied v_med3_u32. ----
__global__ __launch_bounds__(256, 4) void k_phase1(
    const uint32_t* __restrict__ keys, const uint32_t* __restrict__ wmax_bits,
    uint32_t* __restrict__ slots, OvfRec* __restrict__ ovf,
    uint32_t* __restrict__ ovf_cnt) {
  const int lane = threadIdx.x & 63;
  const int wid = __builtin_amdgcn_readfirstlane(
      (int)(blockIdx.x * 4 + (threadIdx.x >> 6)));
  const float wmax = __uint_as_float(
      (uint32_t)__builtin_amdgcn_readfirstlane((int)*wmax_bits));
  const float wEff = wmax + 1e-5f;
  const uint32_t packMask = 0xFFFFFE00u;

  int r = wid;
  if (r >= NROWS) return;
  uint32_t k0c = keys[2 * (r >> 11)], k1c = keys[2 * (r >> 11) + 1];

  for (; r < NROWS; r += NWAVES) {
    // prefetch next row's keys (scalar, independent of this row's compute)
    const int rn = r + NWAVES;
    uint32_t k0n = 0u, k1n = 0u;
    if (rn < NROWS) { k0n = keys[2 * (rn >> 11)]; k1n = keys[2 * (rn >> 11) + 1]; }

    const uint32_t k0 = k0c, k1 = k1c;
    const uint32_t a = (uint32_t)(r & 2047);
    const uint32_t k2 = k0 ^ k1 ^ 0x1BD11BDAu;
    const uint32_t k2_1 = k2 + 1u, k0_2 = k0 + 2u, k1_3 = k1 + 3u;
    const uint32_t k2_4 = k2 + 4u, k0_5 = k0 + 5u;

    // ctr for slot j = a*2048 + j*64 + lane
    const uint32_t vb_k1   = (a << 11) + (uint32_t)lane + k1;  // x1 base
    const uint32_t vb_k1k0 = vb_k1 + k0;                       // x0 base

    uint32_t m1 = 0u, m2 = 0u;   // per-lane top-2 packed (m1 >= m2)
#define TFR(rr) { x0 += x1; x1 = __builtin_rotateleft32(x1, rr) ^ x0; }
#define TFI(kA, kB, rr) { x1 += (kB); x0 = x0 + (kA) + x1; \
                          x1 = __builtin_rotateleft32(x1, rr) ^ x0; }
#pragma unroll
    for (uint32_t slot = 0; slot < 32; ++slot) {
      const uint32_t C = slot << 6;
      uint32_t x1 = vb_k1 + C;
      uint32_t x0 = vb_k1k0 + C;                    // == x1 + k0 (round-1 add)
      x1 = __builtin_rotateleft32(x1, 13) ^ x0;     // round 1 tail
      TFR(15) TFR(26) TFR(6)
      TFI(k1, k2_1, 17)
      TFR(29) TFR(16) TFR(24)
      TFI(k2, k0_2, 13)
      TFR(15) TFR(26) TFR(6)
      TFI(k0, k1_3, 17)
      TFR(29) TFR(16) TFR(24)
      TFI(k1, k2_4, 13)
      TFR(15) TFR(26) TFR(6)
      x0 += k2; x1 += k0_5;
      const uint32_t p = ((x0 ^ x1) & packMask) | slot;   // v_and_or_b32
      // top-2: m2 = med3(m1, m2, p) in place (tied), m1 = max(m1, p)
      asm("v_med3_u32 %0, %1, %0, %2" : "+v"(m2) : "v"(m1), "v"(p));
      m1 = max(m1, p);
    }
#undef TFI
#undef TFR

    // wave max of m1 -> row max
    uint32_t M = m1;
#pragma unroll
    for (int off = 32; off; off >>= 1)
      M = max(M, (uint32_t)__shfl_xor((int)M, off));
    const uint32_t mstar = M >> 9;

    // local-slope candidate window: du <= wEff * max(-u ln u) on [u*-du, u*]
    const float uStar = __uint_as_float(0x3f800000u | (mstar << 9)) - 1.0f;
    uint32_t W;
    if (mstar < 64u) {
      W = 3200u;                       // never hit in practice; safe cap
    } else {
      float f0 = -uStar * logf(uStar);
      float d0 = wEff * f0 * 1.1f + 4e-6f;
      float uLo = uStar - d0;
      float bound;
      if (uLo <= 0.f) bound = 0.36788f;
      else {
        float fLo = -uLo * logf(uLo);
        bound = fmaxf(f0, fLo);
        if (uLo < 0.3679f && uStar > 0.3678f) bound = 0.36788f;  // spans 1/e
      }
      float du = wEff * bound * 1.02f + 2.4e-7f;
      W = (uint32_t)(du * 8388608.0f) + 2u;
    }
    const uint32_t thr_m = (mstar > W) ? (mstar - W) : 0u;
    const uint32_t thrP  = thr_m << 9;

    // exact candidate count from two ballots (tc==1 provably exact)
    unsigned long long bal1 = __ballot(m1 >= thrP);
    unsigned long long bal2 = __ballot(m2 >= thrP);
    int tc = (int)__popcll(bal1) + (int)__popcll(bal2);

    if (tc == 1) {
      int leader = (int)__builtin_ctzll(bal1);
      uint32_t wp = (uint32_t)__shfl((int)m1, leader);
      if (lane == 0) slots[r] = ((wp & 31u) << 6) | (uint32_t)leader;
    } else {  // rare (~2e-3): recompute all slots, record candidate list
      uint32_t idx = 0u;
      if (lane == 0) idx = atomicAdd(ovf_cnt, 1u);
      idx = (uint32_t)__shfl((int)idx, 0);
      if (idx < (uint32_t)OVF_CAP) {
        const uint32_t base = a << 11;
        int off = 0;
#pragma unroll 1
        for (int slot = 0; slot < 32; ++slot) {
          uint2 o = tf2x32(k0, k1, 0u,
                           base + (uint32_t)(slot << 6) + (uint32_t)lane);
          uint32_t m = (o.x ^ o.y) >> 9;
          bool c = (m >= thr_m);
          unsigned long long bal = __ballot(c);
          if (bal) {
            if (c) {
              int pos = off + (int)__popcll(bal & ((1ull << lane) - 1ull));
              if (pos < 16) {
                ovf[idx].n[pos] = ((uint32_t)slot << 6) | (uint32_t)lane;
                ovf[idx].g[pos] = gumbel_from_m(m);
              }
            }
            off += (int)__popcll(bal);
          }
        }
        if (lane == 0) {
          ovf[idx].cnt = (uint32_t)min(off, 16);
          slots[r] = 0x80000000u | idx;
        }
      } else if (lane == 0) {
        int leader = (int)__builtin_ctzll(bal1);
        uint32_t wp = (uint32_t)__shfl((int)m1, leader);
        slots[r] = ((wp & 31u) << 6) | (uint32_t)leader;  // capacity fallback
      }
    }
    k0c = k0n; k1c = k1n;
  }
}

// ---- Phase 2: 2048 independent ants replay the sequential walk ----
__global__ __launch_bounds__(256) void k_phase2(
    const uint32_t* __restrict__ slots, const OvfRec* __restrict__ ovf,
    const float* __restrict__ pher, const float* __restrict__ heur,
    const int* __restrict__ antpos, uint16_t* __restrict__ paths,
    float* __restrict__ plen_out) {
  __shared__ uint32_t vis[256][64];    // 64 KB: per-ant visited bitmap
  const int t = threadIdx.x;
  const int a = blockIdx.x * 256 + t;
  for (int i = 0; i < 64; ++i) vis[t][i] = 0u;
  int cur = antpos[a];
  vis[t][cur >> 5] |= 1u << (cur & 31);
  paths[(size_t)a * NN] = (uint16_t)cur;
  float plen = 0.f;
  for (int s = 0; s < NS; ++s) {
    uint32_t slot = slots[(size_t)s * NA + a];
    int nxt;
    if (!(slot & 0x80000000u)) {
      nxt = (int)slot;
    } else {
      const OvfRec& r = ovf[slot & 0x7fffffffu];
      float bs = -INFINITY; int bn = NN;
      int c = (int)r.cnt;
      for (int i = 0; i < c; ++i) {
        int n = (int)r.n[i];
        float wv = 0.f;
        if (((vis[t][n >> 5] >> (n & 31)) & 1u) == 0u) {
          float h = heur[(size_t)cur * NN + n];
          wv = pher[(size_t)cur * NN + n] * (h * h);
        }
        float sv = r.g[i] + wv;
        if (sv > bs || (sv == bs && n < bn)) { bs = sv; bn = n; }
      }
      nxt = bn;
    }
    plen += heur[(size_t)cur * NN + nxt];   // same fp32 order as reference
    vis[t][nxt >> 5] |= 1u << (nxt & 31);
    paths[(size_t)a * NN + s + 1] = (uint16_t)nxt;
    cur = nxt;
  }
  plen_out[a] = plen;
}

// ---- Final: argmin plen (first-index tie-break), broadcast best path x8 ----
__global__ void k_final(const float* __restrict__ plen,
                        const uint16_t* __restrict__ paths,
                        float* __restrict__ out) {
  __shared__ unsigned long long wred[4];
  const int t = threadIdx.x;  // 256
  unsigned long long best = ~0ull;
  for (int a = t; a < NA; a += 256) {
    unsigned long long k =
        ((unsigned long long)__float_as_uint(plen[a]) << 32) | (unsigned)a;
    if (k < best) best = k;
  }
  for (int off = 32; off; off >>= 1) {
    unsigned long long o = __shfl_xor(best, off);
    if (o < best) best = o;
  }
  if ((t & 63) == 0) wred[t >> 6] = best;
  __syncthreads();
  if (t == 0) {
    unsigned long long b = wred[0];
    for (int i = 1; i < 4; ++i) if (wred[i] < b) b = wred[i];
    wred[0] = b;
  }
  __syncthreads();
  const int bi = (int)(wred[0] & 0xffffffffu);
  const uint16_t* bp = paths + (size_t)bi * NN;
  for (int i = t; i < 8 * NN; i += 256) out[i] = (float)bp[i & (NN - 1)];
}

extern "C" void kernel_launch(void* const* d_in, const int* in_sizes, int n_in,
                              void* d_out, int out_size, void* d_ws, size_t ws_size,
                              hipStream_t stream) {
  (void)in_sizes; (void)n_in; (void)out_size; (void)ws_size;
  const float* pher   = (const float*)d_in[1];
  const float* heur   = (const float*)d_in[2];
  const int*   antpos = (const int*)d_in[3];
  char* ws = (char*)d_ws;
  uint32_t* wmax_bits = (uint32_t*)(ws + 0);
  uint32_t* ovf_cnt   = (uint32_t*)(ws + 4);
  uint32_t* keys      = (uint32_t*)(ws + OFF_KEYS);
  uint32_t* slots     = (uint32_t*)(ws + OFF_SLOTS);
  OvfRec*   ovf       = (OvfRec*)(ws + OFF_OVF);
  uint16_t* paths     = (uint16_t*)(ws + OFF_PATHS);
  float*    plen      = (float*)(ws + OFF_PLEN);

  hipMemsetAsync(d_ws, 0, 64, stream);  // wmax, ovf counter
  hipLaunchKernelGGL(k_keys, dim3(8), dim3(256), 0, stream, keys);
  hipLaunchKernelGGL(k_wmax, dim3(1024), dim3(256), 0, stream, pher, heur, wmax_bits);
  hipLaunchKernelGGL(k_phase1, dim3(NWAVES / 4), dim3(256), 0, stream,
                     keys, wmax_bits, slots, ovf, ovf_cnt);
  hipLaunchKernelGGL(k_phase2, dim3(NA / 256), dim3(256), 0, stream,
                     slots, ovf, pher, heur, antpos, paths, plen);
  hipLaunchKernelGGL(k_final, dim3(1), dim3(256), 0, stream,
                     plen, paths, (float*)d_out);
}

// Round 6
// 14979.222 us; speedup vs baseline: 1.1431x; 1.1431x over previous
//
#include <hip/hip_runtime.h>
#include <stdint.h>
#include <math.h>

constexpr int NN = 2048;   // nodes
constexpr int NA = 2048;   // ants
constexpr int NS = 2047;   // steps (N-1)
constexpr int NROWS = NS * NA;          // 4,192,256 (row id r = s*2048 + a)
constexpr int NWAVES = 2048 * 4;        // persistent: one generation

struct OvfRec { uint32_t cnt; uint32_t n[16]; float g[16]; };

constexpr int    OVF_CAP   = 32768;
constexpr size_t OFF_KEYS  = 1024;
constexpr size_t OFF_SLOTS = 32768;
constexpr size_t OFF_OVF   = OFF_SLOTS + (size_t)NS * NA * 4;
constexpr size_t OFF_PATHS = OFF_OVF + (size_t)OVF_CAP * sizeof(OvfRec);
constexpr size_t OFF_PLEN  = OFF_PATHS + (size_t)NA * NN * 2;
// total ws ~29.5 MB

// ---- Threefry-2x32, 20 rounds (jax partitionable counter mode) ----
__device__ __forceinline__ uint2 tf2x32(uint32_t k0, uint32_t k1,
                                        uint32_t x0, uint32_t x1) {
  const uint32_t k2 = k0 ^ k1 ^ 0x1BD11BDAu;
  x0 += k0; x1 += k1;
#define TFR(r) { x0 += x1; x1 = __builtin_rotateleft32(x1, r) ^ x0; }
  TFR(13) TFR(15) TFR(26) TFR(6)
  x0 += k1; x1 += k2 + 1u;
  TFR(17) TFR(29) TFR(16) TFR(24)
  x0 += k2; x1 += k0 + 2u;
  TFR(13) TFR(15) TFR(26) TFR(6)
  x0 += k0; x1 += k1 + 3u;
  TFR(17) TFR(29) TFR(16) TFR(24)
  x0 += k1; x1 += k2 + 4u;
  TFR(13) TFR(15) TFR(26) TFR(6)
  x0 += k2; x1 += k0 + 5u;
#undef TFR
  return make_uint2(x0, x1);
}

// g = -log(-log(u)), fp32 intermediate rounding via double log (matches XLA
// f32 log to ~1 ulp); u from 23-bit mantissa m, u==0 -> tiny.
__device__ __forceinline__ float gumbel_from_m(uint32_t m) {
  float u = __uint_as_float(0x3f800000u | m) - 1.0f;
  if (m == 0u) u = 1.17549435e-38f;
  float t1 = (float)log((double)u);
  float t2 = (float)log(-(double)t1);
  return -t2;
}

// ---- per-step keys: jax.random.split(key(42), 2047), partitionable ----
__global__ void k_keys(uint32_t* __restrict__ keys) {
  int i = blockIdx.x * 256 + threadIdx.x;
  if (i >= NS) return;
  uint2 o = tf2x32(0u, 42u, 0u, (uint32_t)i);
  keys[2 * i] = o.x; keys[2 * i + 1] = o.y;
}

// ---- global max of weights = pher * heur^2 ----
__global__ void k_wmax(const float* __restrict__ pher, const float* __restrict__ heur,
                       uint32_t* __restrict__ wmax_bits) {
  int tid = blockIdx.x * blockDim.x + threadIdx.x;
  int stride = gridDim.x * blockDim.x;
  float m = 0.f;
  for (int i = tid; i < NN * NN; i += stride) {
    float h = heur[i];
    m = fmaxf(m, pher[i] * (h * h));
  }
  for (int off = 32; off; off >>= 1) m = fmaxf(m, __shfl_xor(m, off));
  if ((threadIdx.x & 63) == 0) atomicMax((unsigned int*)wmax_bits, __float_as_uint(m));
}

// Hot-loop threefry round with FORCED v_alignbit_b32 (rotl r == alignbit
// shift 32-r) and FORCED v_add3_u32 for the key-injection fold. sr = 32-rotl.
#define TFRA(sr) { x0 += x1; uint32_t _t;                                   \
  asm("v_alignbit_b32 %0, %1, %1, " #sr : "=v"(_t) : "v"(x1));              \
  x1 = _t ^ x0; }
#define TFIA(kA, kB, sr) { x1 += (kB);                                      \
  asm("v_add3_u32 %0, %0, %1, %2" : "+v"(x0) : "s"(kA), "v"(x1));           \
  uint32_t _t;                                                              \
  asm("v_alignbit_b32 %0, %1, %1, " #sr : "=v"(_t) : "v"(x1));              \
  x1 = _t ^ x0; }

// ---- Phase 1: persistent waves, one wave per row iteration. Per-lane top-2
// via tied v_med3_u32; rotates/injections pinned to fused opcodes. ----
__global__ __launch_bounds__(256, 4) void k_phase1(
    const uint32_t* __restrict__ keys, const uint32_t* __restrict__ wmax_bits,
    uint32_t* __restrict__ slots, OvfRec* __restrict__ ovf,
    uint32_t* __restrict__ ovf_cnt) {
  const int lane = threadIdx.x & 63;
  const int wid = __builtin_amdgcn_readfirstlane(
      (int)(blockIdx.x * 4 + (threadIdx.x >> 6)));
  const float wmax = __uint_as_float(
      (uint32_t)__builtin_amdgcn_readfirstlane((int)*wmax_bits));
  const float wEff = wmax + 1e-5f;
  const uint32_t packMask = 0xFFFFFE00u;

  int r = wid;
  if (r >= NROWS) return;
  uint32_t k0c = keys[2 * (r >> 11)], k1c = keys[2 * (r >> 11) + 1];

  for (; r < NROWS; r += NWAVES) {
    // prefetch next row's keys (scalar, independent of this row's compute)
    const int rn = r + NWAVES;
    uint32_t k0n = 0u, k1n = 0u;
    if (rn < NROWS) { k0n = keys[2 * (rn >> 11)]; k1n = keys[2 * (rn >> 11) + 1]; }

    const uint32_t k0 = k0c, k1 = k1c;
    const uint32_t a = (uint32_t)(r & 2047);
    const uint32_t k2 = k0 ^ k1 ^ 0x1BD11BDAu;
    const uint32_t k2_1 = k2 + 1u, k0_2 = k0 + 2u, k1_3 = k1 + 3u;
    const uint32_t k2_4 = k2 + 4u, k0_5 = k0 + 5u;

    // ctr for slot j = a*2048 + j*64 + lane
    const uint32_t vb_k1 = (a << 11) + (uint32_t)lane + k1;  // x1 base

    uint32_t m1 = 0u, m2 = 0u;   // per-lane top-2 packed (m1 >= m2)
#pragma unroll
    for (uint32_t slot = 0; slot < 32; ++slot) {
      uint32_t x1 = vb_k1 + (slot << 6);
      uint32_t x0 = x1 + k0;                       // round-1 add (x0 init = k0)
      { uint32_t _t;                               // round-1 tail: rotl13
        asm("v_alignbit_b32 %0, %1, %1, 19" : "=v"(_t) : "v"(x1));
        x1 = _t ^ x0; }
      TFRA(17) TFRA(6) TFRA(26)      // rotl 15, 26, 6
      TFIA(k1, k2_1, 15)             // inj1 + rotl17
      TFRA(3) TFRA(16) TFRA(8)       // rotl 29, 16, 24
      TFIA(k2, k0_2, 19)             // inj2 + rotl13
      TFRA(17) TFRA(6) TFRA(26)      // rotl 15, 26, 6
      TFIA(k0, k1_3, 15)             // inj3 + rotl17
      TFRA(3) TFRA(16) TFRA(8)       // rotl 29, 16, 24
      TFIA(k1, k2_4, 19)             // inj4 + rotl13
      TFRA(17) TFRA(6) TFRA(26)      // rotl 15, 26, 6
      x0 += k2; x1 += k0_5;          // final injection
      const uint32_t p = ((x0 ^ x1) & packMask) | slot;   // v_and_or_b32
      // top-2: m2 = med3(m1, m2, p) in place (tied), m1 = max(m1, p)
      asm("v_med3_u32 %0, %1, %0, %2" : "+v"(m2) : "v"(m1), "v"(p));
      m1 = max(m1, p);
    }

    // wave max of m1 -> row max
    uint32_t M = m1;
#pragma unroll
    for (int off = 32; off; off >>= 1)
      M = max(M, (uint32_t)__shfl_xor((int)M, off));
    const uint32_t mstar = M >> 9;

    // local-slope candidate window: du <= wEff * max(-u ln u) on [u*-du, u*]
    const float uStar = __uint_as_float(0x3f800000u | (mstar << 9)) - 1.0f;
    uint32_t W;
    if (mstar < 64u) {
      W = 3200u;                       // never hit in practice; safe cap
    } else {
      float f0 = -uStar * logf(uStar);
      float d0 = wEff * f0 * 1.1f + 4e-6f;
      float uLo = uStar - d0;
      float bound;
      if (uLo <= 0.f) bound = 0.36788f;
      else {
        float fLo = -uLo * logf(uLo);
        bound = fmaxf(f0, fLo);
        if (uLo < 0.3679f && uStar > 0.3678f) bound = 0.36788f;  // spans 1/e
      }
      float du = wEff * bound * 1.02f + 2.4e-7f;
      W = (uint32_t)(du * 8388608.0f) + 2u;
    }
    const uint32_t thr_m = (mstar > W) ? (mstar - W) : 0u;
    const uint32_t thrP  = thr_m << 9;

    // exact candidate count from two ballots (tc==1 provably exact)
    unsigned long long bal1 = __ballot(m1 >= thrP);
    unsigned long long bal2 = __ballot(m2 >= thrP);
    int tc = (int)__popcll(bal1) + (int)__popcll(bal2);

    if (tc == 1) {
      int leader = (int)__builtin_ctzll(bal1);
      uint32_t wp = (uint32_t)__shfl((int)m1, leader);
      if (lane == 0) slots[r] = ((wp & 31u) << 6) | (uint32_t)leader;
    } else {  // rare (~2e-3): recompute all slots, record candidate list
      uint32_t idx = 0u;
      if (lane == 0) idx = atomicAdd(ovf_cnt, 1u);
      idx = (uint32_t)__shfl((int)idx, 0);
      if (idx < (uint32_t)OVF_CAP) {
        const uint32_t base = a << 11;
        int off = 0;
#pragma unroll 1
        for (int slot = 0; slot < 32; ++slot) {
          uint2 o = tf2x32(k0c, k1c, 0u,
                           base + (uint32_t)(slot << 6) + (uint32_t)lane);
          uint32_t m = (o.x ^ o.y) >> 9;
          bool c = (m >= thr_m);
          unsigned long long bal = __ballot(c);
          if (bal) {
            if (c) {
              int pos = off + (int)__popcll(bal & ((1ull << lane) - 1ull));
              if (pos < 16) {
                ovf[idx].n[pos] = ((uint32_t)slot << 6) | (uint32_t)lane;
                ovf[idx].g[pos] = gumbel_from_m(m);
              }
            }
            off += (int)__popcll(bal);
          }
        }
        if (lane == 0) {
          ovf[idx].cnt = (uint32_t)min(off, 16);
          slots[r] = 0x80000000u | idx;
        }
      } else if (lane == 0) {
        int leader = (int)__builtin_ctzll(bal1);
        uint32_t wp = (uint32_t)__shfl((int)m1, leader);
        slots[r] = ((wp & 31u) << 6) | (uint32_t)leader;  // capacity fallback
      }
    }
    k0c = k0n; k1c = k1n;
  }
}

// ---- Phase 2: 2048 independent ants replay the sequential walk ----
__global__ __launch_bounds__(256) void k_phase2(
    const uint32_t* __restrict__ slots, const OvfRec* __restrict__ ovf,
    const float* __restrict__ pher, const float* __restrict__ heur,
    const int* __restrict__ antpos, uint16_t* __restrict__ paths,
    float* __restrict__ plen_out) {
  __shared__ uint32_t vis[256][64];    // 64 KB: per-ant visited bitmap
  const int t = threadIdx.x;
  const int a = blockIdx.x * 256 + t;
  for (int i = 0; i < 64; ++i) vis[t][i] = 0u;
  int cur = antpos[a];
  vis[t][cur >> 5] |= 1u << (cur & 31);
  paths[(size_t)a * NN] = (uint16_t)cur;
  float plen = 0.f;
  for (int s = 0; s < NS; ++s) {
    uint32_t slot = slots[(size_t)s * NA + a];
    int nxt;
    if (!(slot & 0x80000000u)) {
      nxt = (int)slot;
    } else {
      const OvfRec& r = ovf[slot & 0x7fffffffu];
      float bs = -INFINITY; int bn = NN;
      int c = (int)r.cnt;
      for (int i = 0; i < c; ++i) {
        int n = (int)r.n[i];
        float wv = 0.f;
        if (((vis[t][n >> 5] >> (n & 31)) & 1u) == 0u) {
          float h = heur[(size_t)cur * NN + n];
          wv = pher[(size_t)cur * NN + n] * (h * h);
        }
        float sv = r.g[i] + wv;
        if (sv > bs || (sv == bs && n < bn)) { bs = sv; bn = n; }
      }
      nxt = bn;
    }
    plen += heur[(size_t)cur * NN + nxt];   // same fp32 order as reference
    vis[t][nxt >> 5] |= 1u << (nxt & 31);
    paths[(size_t)a * NN + s + 1] = (uint16_t)nxt;
    cur = nxt;
  }
  plen_out[a] = plen;
}

// ---- Final: argmin plen (first-index tie-break), broadcast best path x8 ----
__global__ void k_final(const float* __restrict__ plen,
                        const uint16_t* __restrict__ paths,
                        float* __restrict__ out) {
  __shared__ unsigned long long wred[4];
  const int t = threadIdx.x;  // 256
  unsigned long long best = ~0ull;
  for (int a = t; a < NA; a += 256) {
    unsigned long long k =
        ((unsigned long long)__float_as_uint(plen[a]) << 32) | (unsigned)a;
    if (k < best) best = k;
  }
  for (int off = 32; off; off >>= 1) {
    unsigned long long o = __shfl_xor(best, off);
    if (o < best) best = o;
  }
  if ((t & 63) == 0) wred[t >> 6] = best;
  __syncthreads();
  if (t == 0) {
    unsigned long long b = wred[0];
    for (int i = 1; i < 4; ++i) if (wred[i] < b) b = wred[i];
    wred[0] = b;
  }
  __syncthreads();
  const int bi = (int)(wred[0] & 0xffffffffu);
  const uint16_t* bp = paths + (size_t)bi * NN;
  for (int i = t; i < 8 * NN; i += 256) out[i] = (float)bp[i & (NN - 1)];
}

extern "C" void kernel_launch(void* const* d_in, const int* in_sizes, int n_in,
                              void* d_out, int out_size, void* d_ws, size_t ws_size,
                              hipStream_t stream) {
  (void)in_sizes; (void)n_in; (void)out_size; (void)ws_size;
  const float* pher   = (const float*)d_in[1];
  const float* heur   = (const float*)d_in[2];
  const int*   antpos = (const int*)d_in[3];
  char* ws = (char*)d_ws;
  uint32_t* wmax_bits = (uint32_t*)(ws + 0);
  uint32_t* ovf_cnt   = (uint32_t*)(ws + 4);
  uint32_t* keys      = (uint32_t*)(ws + OFF_KEYS);
  uint32_t* slots     = (uint32_t*)(ws + OFF_SLOTS);
  OvfRec*   ovf       = (OvfRec*)(ws + OFF_OVF);
  uint16_t* paths     = (uint16_t*)(ws + OFF_PATHS);
  float*    plen      = (float*)(ws + OFF_PLEN);

  hipMemsetAsync(d_ws, 0, 64, stream);  // wmax, ovf counter
  hipLaunchKernelGGL(k_keys, dim3(8), dim3(256), 0, stream, keys);
  hipLaunchKernelGGL(k_wmax, dim3(1024), dim3(256), 0, stream, pher, heur, wmax_bits);
  hipLaunchKernelGGL(k_phase1, dim3(NWAVES / 4), dim3(256), 0, stream,
                     keys, wmax_bits, slots, ovf, ovf_cnt);
  hipLaunchKernelGGL(k_phase2, dim3(NA / 256), dim3(256), 0, stream,
                     slots, ovf, pher, heur, antpos, paths, plen);
  hipLaunchKernelGGL(k_final, dim3(1), dim3(256), 0, stream,
                     plen, paths, (float*)d_out);
}